// Round 1
// baseline (1044.738 us; speedup 1.0000x reference)
//
#include <hip/hip_runtime.h>
#include <cstdint>
#include <cstddef>

#define DINL __device__ __forceinline__

typedef float f32x4 __attribute__((ext_vector_type(4)));
typedef unsigned short u16x8 __attribute__((ext_vector_type(8)));
typedef __bf16 bf16x8 __attribute__((ext_vector_type(8)));
typedef _Float16 half2v __attribute__((ext_vector_type(2)));

static constexpr int I_SZ  = 2016;
static constexpr int G4H   = 400;   // 4*HIDDEN
static constexpr int HID   = 100;
static constexpr int BATCH = 256;
static constexpr int TLEN  = 256;
static constexpr int MROWS = BATCH * TLEN;  // 65536
static constexpr int KT    = 63;            // 2016 / 32
static constexpr int NPAD  = 512;           // padded gate dim for staging
static constexpr int LD    = 40;            // K-stride in ushorts (80 B, 16B-aligned, breaks pow2 bank pattern)

DINL unsigned short f2bf(float f) {
  unsigned u = __float_as_uint(f);
  u += 0x7fffu + ((u >> 16) & 1u);   // RNE
  return (unsigned short)(u >> 16);
}
DINL float bf2f(unsigned short v) { return __uint_as_float(((unsigned)v) << 16); }

DINL void async16(const unsigned short* g, unsigned short* l) {
  __builtin_amdgcn_global_load_lds(
      (const __attribute__((address_space(1))) unsigned int*)g,
      (__attribute__((address_space(3))) unsigned int*)l, 16, 0, 0);
}

#if __has_builtin(__builtin_amdgcn_fdot2)
DINL float fdot2f(half2v a, half2v b, float c) { return __builtin_amdgcn_fdot2(a, b, c, false); }
#else
DINL float fdot2f(half2v a, half2v b, float c) {
  return c + (float)a[0] * (float)b[0] + (float)a[1] * (float)b[1];
}
#endif

#if __has_builtin(__builtin_amdgcn_exp2f)
DINL float ex2(float x) { return __builtin_amdgcn_exp2f(x); }
#else
DINL float ex2(float x) { return exp2f(x); }
#endif
#if __has_builtin(__builtin_amdgcn_rcpf)
DINL float rcpf_(float x) { return __builtin_amdgcn_rcpf(x); }
#else
DINL float rcpf_(float x) { return 1.0f / x; }
#endif

DINL float fast_sigmoid(float x) { return rcpf_(1.0f + ex2(-1.44269504f * x)); }
DINL float fast_tanh(float x)    { return 1.0f - 2.0f * rcpf_(1.0f + ex2(2.88539008f * x)); }

DINL half2v bch2(unsigned v) { return __builtin_bit_cast(half2v, v); }

// ---------------------------------------------------------------------------
// Kernel 0: pack W_ih (fp32 [400][2016]) -> Wb bf16, layout [63 ktiles][512 cols][40 k]
// (col-major within k-tile so MFMA B-frag reads are contiguous ds_read_b128),
// and biasb[512] = b_ih + b_hh (zero padded).
// ---------------------------------------------------------------------------
__global__ void prep_kernel(const float* __restrict__ W_ih,
                            const float* __restrict__ b_ih,
                            const float* __restrict__ b_hh,
                            unsigned short* __restrict__ Wb,
                            float* __restrict__ biasb) {
  int idx = blockIdx.x * 256 + threadIdx.x;
  const int total = KT * NPAD * LD;
  if (idx < total) {
    int kt = idx / (NPAD * LD);
    int r  = idx - kt * (NPAD * LD);
    int n  = r / LD;
    int kk = r - n * LD;
    unsigned short v = 0;
    if (n < G4H && kk < 32) v = f2bf(W_ih[n * I_SZ + kt * 32 + kk]);
    Wb[idx] = v;
  }
  if (idx < NPAD) biasb[idx] = (idx < G4H) ? (b_ih[idx] + b_hh[idx]) : 0.0f;
}

// ---------------------------------------------------------------------------
// Kernel 1: x_proj = bf16( x @ W_ih^T + bias ), stored bf16 [65536][400].
// Tile: 128 rows x 416 cols (13 N-frags x 2 N-waves, uniform trip count),
// BK=32 (one 16x16x32 MFMA K-chunk), double-buffered LDS, 8 waves.
// ---------------------------------------------------------------------------
__global__ __launch_bounds__(512) void gemm_xproj(
    const float* __restrict__ x, const unsigned short* __restrict__ Wb,
    const float* __restrict__ biasb, unsigned short* __restrict__ xp) {
  __shared__ unsigned short Ab[2][128 * LD];   // 2 x 10240 B
  __shared__ unsigned short Bb[2][NPAD * LD];  // 2 x 40960 B

  const int tid  = threadIdx.x;
  const int lane = tid & 63;
  const int wv   = tid >> 6;   // 0..7
  const int wm   = wv & 3;     // 4 waves in M
  const int wn   = wv >> 2;    // 2 waves in N
  const int m0   = blockIdx.x * 128;
  const int arow = tid >> 2;   // 0..127
  const int akq  = tid & 3;    // 8 floats each
  const int l15  = lane & 15;
  const int l4   = lane >> 4;

  f32x4 acc[2][13];
#pragma unroll
  for (int i = 0; i < 2; ++i)
#pragma unroll
    for (int j = 0; j < 13; ++j) acc[i][j] = (f32x4){0.f, 0.f, 0.f, 0.f};

  float4 a0, a1;
  const float* xr = x + (size_t)(m0 + arow) * I_SZ + akq * 8;

  auto loadA = [&](int kt) {
    const float* p = xr + kt * 32;
    a0 = *(const float4*)p;
    a1 = *(const float4*)(p + 4);
  };
  auto stageB = [&](int kt, int nb) {
    const unsigned short* src = Wb + (size_t)kt * (NPAD * LD) + lane * 8;
    unsigned short* dst = &Bb[nb][0];
#pragma unroll
    for (int i = 0; i < 5; ++i) {
      int c = wv + 8 * i;  // 40 chunks of 1 KiB
      async16(src + c * 512, dst + c * 512);
    }
  };
  auto writeA = [&](int nb) {
    u16x8 u;
    u[0] = f2bf(a0.x); u[1] = f2bf(a0.y); u[2] = f2bf(a0.z); u[3] = f2bf(a0.w);
    u[4] = f2bf(a1.x); u[5] = f2bf(a1.y); u[6] = f2bf(a1.z); u[7] = f2bf(a1.w);
    *(u16x8*)&Ab[nb][arow * LD + akq * 8] = u;
  };

  loadA(0);
  stageB(0, 0);
  writeA(0);
  __syncthreads();

  int cur = 0;
  for (int kt = 0; kt < KT; ++kt) {
    if (kt < KT - 1) { loadA(kt + 1); stageB(kt + 1, cur ^ 1); }
    bf16x8 af0 = __builtin_bit_cast(bf16x8, *(const u16x8*)&Ab[cur][(wm * 32 + l15) * LD + l4 * 8]);
    bf16x8 af1 = __builtin_bit_cast(bf16x8, *(const u16x8*)&Ab[cur][(wm * 32 + 16 + l15) * LD + l4 * 8]);
#pragma unroll
    for (int nf = 0; nf < 13; ++nf) {
      bf16x8 bfr = __builtin_bit_cast(bf16x8,
          *(const u16x8*)&Bb[cur][(wn * 208 + nf * 16 + l15) * LD + l4 * 8]);
      acc[0][nf] = __builtin_amdgcn_mfma_f32_16x16x32_bf16(af0, bfr, acc[0][nf], 0, 0, 0);
      acc[1][nf] = __builtin_amdgcn_mfma_f32_16x16x32_bf16(af1, bfr, acc[1][nf], 0, 0, 0);
    }
    if (kt < KT - 1) writeA(cur ^ 1);
    __syncthreads();
    cur ^= 1;
  }

  // epilogue: C/D layout col = lane&15, row = (lane>>4)*4 + r  [verified m89]
#pragma unroll
  for (int mf = 0; mf < 2; ++mf) {
#pragma unroll
    for (int nf = 0; nf < 13; ++nf) {
      int colf = wn * 208 + nf * 16;
      if (colf < G4H) {   // wn=1,nf=12 covers cols 400..415 -> dropped
        int col = colf + l15;
        float bias = biasb[col];
        int row = m0 + wm * 32 + mf * 16 + l4 * 4;
#pragma unroll
        for (int r = 0; r < 4; ++r)
          xp[(size_t)(row + r) * G4H + col] = f2bf(acc[mf][nf][r] + bias);
      }
    }
  }
}

// ---------------------------------------------------------------------------
// Kernel 2: LSTM recurrence + final FC. One workgroup per batch element.
// Thread g < 400 owns gate row g of W_hh in registers as 50 half2;
// h broadcast through LDS as f16, dot via v_dot2_f32_f16 (4 acc chains).
// Thread j < 100 owns c[j] in a register.
// ---------------------------------------------------------------------------
__global__ __launch_bounds__(512) void lstm_rec(
    const unsigned short* __restrict__ xp, const float* __restrict__ W_hh,
    const float* __restrict__ W_fc, const float* __restrict__ b_fc,
    float* __restrict__ out) {
  __shared__ __align__(16) _Float16 h_lds[104];  // padded to 13 x uint4, pads stay 0
  __shared__ float act[G4H];

  const int tid = threadIdx.x;
  const int b   = blockIdx.x;
  const int g   = tid;

  half2v w2[52];
  if (g < G4H) {
    const float* wr = W_hh + g * HID;   // row stride 400 B, 16B-aligned
#pragma unroll
    for (int j = 0; j < 25; ++j) {
      float4 v = *(const float4*)(wr + 4 * j);
      w2[2 * j]     = (half2v){(_Float16)v.x, (_Float16)v.y};
      w2[2 * j + 1] = (half2v){(_Float16)v.z, (_Float16)v.w};
    }
    w2[50] = (half2v){(_Float16)0.f, (_Float16)0.f};
    w2[51] = (half2v){(_Float16)0.f, (_Float16)0.f};
  }
  if (tid < 104) h_lds[tid] = (_Float16)0.f;

  float c = 0.f, hreg = 0.f;
  unsigned short xpc = 0;
  if (g < G4H) xpc = xp[((size_t)b * TLEN + 0) * G4H + g];
  __syncthreads();

  for (int t = 0; t < TLEN; ++t) {
    unsigned short xpn = 0;
    if (t + 1 < TLEN && g < G4H)
      xpn = xp[((size_t)b * TLEN + t + 1) * G4H + g];   // prefetch next step

    if (g < G4H) {
      float s0 = bf2f(xpc), s1 = 0.f, s2 = 0.f, s3 = 0.f;
      const uint4* hv = (const uint4*)h_lds;
#pragma unroll
      for (int i = 0; i < 13; ++i) {
        uint4 u = hv[i];  // 8 halves, broadcast read
        s0 = fdot2f(bch2(u.x), w2[4 * i + 0], s0);
        s1 = fdot2f(bch2(u.y), w2[4 * i + 1], s1);
        s2 = fdot2f(bch2(u.z), w2[4 * i + 2], s2);
        s3 = fdot2f(bch2(u.w), w2[4 * i + 3], s3);
      }
      float pre = (s0 + s1) + (s2 + s3);
      // gate order (i,f,g,o): sigmoid, sigmoid, tanh, sigmoid
      float a = (g < 200 || g >= 300) ? fast_sigmoid(pre) : fast_tanh(pre);
      act[g] = a;
    }
    __syncthreads();
    if (tid < HID) {
      float i_ = act[tid], f_ = act[tid + 100], g_ = act[tid + 200], o_ = act[tid + 300];
      c = f_ * c + i_ * g_;
      hreg = o_ * fast_tanh(c);
      h_lds[tid] = (_Float16)hreg;
    }
    __syncthreads();
    xpc = xpn;
  }

  // final FC: out[b][j] = h . W_fc[j] + b_fc[j]
  if (tid < HID) act[tid] = hreg;
  __syncthreads();
  if (tid < 3) {
    float s = b_fc[tid];
    const float* wf = W_fc + tid * HID;
    for (int k = 0; k < HID; ++k) s += wf[k] * act[k];
    out[b * 3 + tid] = s;
  }
}

// ---------------------------------------------------------------------------
extern "C" void kernel_launch(void* const* d_in, const int* in_sizes, int n_in,
                              void* d_out, int out_size, void* d_ws, size_t ws_size,
                              hipStream_t stream) {
  const float* x    = (const float*)d_in[0];
  const float* W_ih = (const float*)d_in[1];
  const float* W_hh = (const float*)d_in[2];
  const float* b_ih = (const float*)d_in[3];
  const float* b_hh = (const float*)d_in[4];
  const float* W_fc = (const float*)d_in[5];
  const float* b_fc = (const float*)d_in[6];
  float* out = (float*)d_out;

  // workspace layout (all 16B-aligned):
  //   xp    : bf16 [65536][400]          = 52,428,800 B
  //   Wb    : bf16 [63][512][40]         =  2,580,480 B
  //   biasb : f32  [512]                 =      2,048 B
  unsigned short* xp = (unsigned short*)d_ws;
  unsigned short* Wb = xp + (size_t)MROWS * G4H;
  float* biasb = (float*)(Wb + (size_t)KT * NPAD * LD);

  prep_kernel<<<(KT * NPAD * LD + 255) / 256, 256, 0, stream>>>(W_ih, b_ih, b_hh, Wb, biasb);
  gemm_xproj<<<MROWS / 128, 512, 0, stream>>>(x, Wb, biasb, xp);
  lstm_rec<<<BATCH, 512, 0, stream>>>(xp, W_hh, W_fc, b_fc, out);
}

// Round 11
// 1028.297 us; speedup vs baseline: 1.0160x; 1.0160x over previous
//
#include <hip/hip_runtime.h>
#include <cstdint>
#include <cstddef>

#define DINL __device__ __forceinline__

typedef float f32x4 __attribute__((ext_vector_type(4)));
typedef unsigned short u16x8 __attribute__((ext_vector_type(8)));
typedef __bf16 bf16x8 __attribute__((ext_vector_type(8)));
typedef _Float16 half2v __attribute__((ext_vector_type(2)));

static constexpr int I_SZ  = 2016;
static constexpr int G4H   = 400;   // 4*HIDDEN
static constexpr int HID   = 100;
static constexpr int BATCH = 256;
static constexpr int TLEN  = 256;
static constexpr int MROWS = BATCH * TLEN;  // 65536
static constexpr int KT    = 63;            // 2016 / 32
static constexpr int NPADW = 416;           // padded gate dim in Wb (stage covers 410)
static constexpr int LD    = 40;            // K-stride in ushorts (80 B: 16B-aligned, 5 mod 8 -> conflict-free b128)
static constexpr int BSTG  = 16384;         // staged B shorts per k-tile (32 KiB = 32 chunks of 1 KiB)

DINL unsigned short f2bf(float f) {
  unsigned u = __float_as_uint(f);
  u += 0x7fffu + ((u >> 16) & 1u);   // RNE
  return (unsigned short)(u >> 16);
}
DINL float bf2f(unsigned short v) { return __uint_as_float(((unsigned)v) << 16); }

DINL void async16(const unsigned short* g, unsigned short* l) {
  __builtin_amdgcn_global_load_lds(
      (const __attribute__((address_space(1))) unsigned int*)g,
      (__attribute__((address_space(3))) unsigned int*)l, 16, 0, 0);
}

#if __has_builtin(__builtin_amdgcn_fdot2)
DINL float fdot2f(half2v a, half2v b, float c) { return __builtin_amdgcn_fdot2(a, b, c, false); }
#else
DINL float fdot2f(half2v a, half2v b, float c) {
  return c + (float)a[0] * (float)b[0] + (float)a[1] * (float)b[1];
}
#endif

#if __has_builtin(__builtin_amdgcn_exp2f)
DINL float ex2(float x) { return __builtin_amdgcn_exp2f(x); }
#else
DINL float ex2(float x) { return exp2f(x); }
#endif
#if __has_builtin(__builtin_amdgcn_rcpf)
DINL float rcpf_(float x) { return __builtin_amdgcn_rcpf(x); }
#else
DINL float rcpf_(float x) { return 1.0f / x; }
#endif

DINL float fast_sigmoid(float x) { return rcpf_(1.0f + ex2(-1.44269504f * x)); }
DINL float fast_tanh(float x)    { return 1.0f - 2.0f * rcpf_(1.0f + ex2(2.88539008f * x)); }

DINL half2v bch2(unsigned v) { return __builtin_bit_cast(half2v, v); }

// ---------------------------------------------------------------------------
// Kernel 0: pack W_ih (fp32 [400][2016]) -> Wb bf16, layout [63 ktiles][416 cols][40 k]
// and biasb[416] = b_ih + b_hh (zero padded).
// ---------------------------------------------------------------------------
__global__ void prep_kernel(const float* __restrict__ W_ih,
                            const float* __restrict__ b_ih,
                            const float* __restrict__ b_hh,
                            unsigned short* __restrict__ Wb,
                            float* __restrict__ biasb) {
  int idx = blockIdx.x * 256 + threadIdx.x;
  const int total = KT * NPADW * LD;
  if (idx < total) {
    int kt = idx / (NPADW * LD);
    int r  = idx - kt * (NPADW * LD);
    int n  = r / LD;
    int kk = r - n * LD;
    unsigned short v = 0;
    if (n < G4H && kk < 32) v = f2bf(W_ih[n * I_SZ + kt * 32 + kk]);
    Wb[idx] = v;
  }
  if (idx < NPADW) biasb[idx] = (idx < G4H) ? (b_ih[idx] + b_hh[idx]) : 0.0f;
}

// ---------------------------------------------------------------------------
// Kernel 1: x_proj = bf16( x @ W_ih^T + bias ), stored bf16 [65536][400].
// Tile 128M x 400N exactly (25 N-frags split 7/6/6/6 over 4 N-waves),
// waves 2M x 4N, BK=32, double-buffered LDS, 8 waves, 512 threads.
// Per-iter per-CU cost model: HBM A-stream 16 KB (~1600 cy) dominates;
// LDS pipe ~1150 cy; MFMA ~970 cy -> HBM-bound ~84 us over 2 block-rounds.
// ---------------------------------------------------------------------------
__global__ __launch_bounds__(512, 2) void gemm_xproj(
    const float* __restrict__ x, const unsigned short* __restrict__ Wb,
    const float* __restrict__ biasb, unsigned short* __restrict__ xp) {
  __shared__ __align__(16) unsigned short Ab[2][128 * LD];  // 2 x 10,240 B
  __shared__ __align__(16) unsigned short Bb[2][BSTG];      // 2 x 32,768 B

  const int tid  = threadIdx.x;
  const int lane = tid & 63;
  const int wv   = tid >> 6;   // 0..7
  const int wn   = wv & 3;     // 4 waves in N
  const int wm   = wv >> 2;    // 2 waves in M (64 rows each)
  const int m0   = blockIdx.x * 128;
  const int arow = tid >> 2;   // 0..127
  const int akq  = tid & 3;    // 8 floats each
  const int l15  = lane & 15;
  const int l4   = lane >> 4;

  const int fst  = wn * 6 + (wn > 0);        // 0,7,13,19
  const int fcnt = 7 - (wn > 0);             // 7,6,6,6

  f32x4 acc[4][7];
#pragma unroll
  for (int i = 0; i < 4; ++i)
#pragma unroll
    for (int j = 0; j < 7; ++j) acc[i][j] = (f32x4){0.f, 0.f, 0.f, 0.f};

  float4 a0, a1;
  const float* xr = x + (size_t)(m0 + arow) * I_SZ + akq * 8;

  auto loadA = [&](int kt) {
    const float* p = xr + kt * 32;
    a0 = *(const float4*)p;
    a1 = *(const float4*)(p + 4);
  };
  auto stageB = [&](int kt, int nb) {
    const unsigned short* src = Wb + (size_t)kt * (NPADW * LD) + lane * 8;
    unsigned short* dst = &Bb[nb][0];
#pragma unroll
    for (int i = 0; i < 4; ++i) {
      int c = wv + 8 * i;  // 32 chunks of 1 KiB
      async16(src + c * 512, dst + c * 512);
    }
  };
  auto writeA = [&](int nb) {
    u16x8 u;
    u[0] = f2bf(a0.x); u[1] = f2bf(a0.y); u[2] = f2bf(a0.z); u[3] = f2bf(a0.w);
    u[4] = f2bf(a1.x); u[5] = f2bf(a1.y); u[6] = f2bf(a1.z); u[7] = f2bf(a1.w);
    *(u16x8*)&Ab[nb][arow * LD + akq * 8] = u;
  };

  loadA(0);
  stageB(0, 0);
  writeA(0);
  __syncthreads();

  int cur = 0;
  for (int kt = 0; kt < KT; ++kt) {
    if (kt < KT - 1) { loadA(kt + 1); stageB(kt + 1, cur ^ 1); }
    bf16x8 af[4];
#pragma unroll
    for (int mf = 0; mf < 4; ++mf)
      af[mf] = __builtin_bit_cast(bf16x8,
          *(const u16x8*)&Ab[cur][(wm * 64 + mf * 16 + l15) * LD + l4 * 8]);
#pragma unroll
    for (int j = 0; j < 7; ++j) {
      if (j < fcnt) {   // wave-uniform guard, static acc index
        bf16x8 bfr = __builtin_bit_cast(bf16x8,
            *(const u16x8*)&Bb[cur][((fst + j) * 16 + l15) * LD + l4 * 8]);
#pragma unroll
        for (int mf = 0; mf < 4; ++mf)
          acc[mf][j] = __builtin_amdgcn_mfma_f32_16x16x32_bf16(af[mf], bfr, acc[mf][j], 0, 0, 0);
      }
    }
    if (kt < KT - 1) writeA(cur ^ 1);
    __syncthreads();
    cur ^= 1;
  }

  // epilogue: C/D layout col = lane&15, row = (lane>>4)*4 + r  [verified m89]
#pragma unroll
  for (int mf = 0; mf < 4; ++mf) {
#pragma unroll
    for (int j = 0; j < 7; ++j) {
      if (j < fcnt) {
        int col = (fst + j) * 16 + l15;          // always < 400
        float bias = biasb[col];
        int row = m0 + wm * 64 + mf * 16 + l4 * 4;
#pragma unroll
        for (int r = 0; r < 4; ++r)
          xp[(size_t)(row + r) * G4H + col] = f2bf(acc[mf][j][r] + bias);
      }
    }
  }
}

// ---------------------------------------------------------------------------
// Kernel 2: LSTM recurrence + final FC. One workgroup (448 thr) per batch elem.
// Thread g < 400 owns gate row g of W_hh in registers as 50 half2;
// h broadcast through LDS as f16, dot via v_dot2_f32_f16 (4 acc chains).
// ---------------------------------------------------------------------------
__global__ __launch_bounds__(448, 2) void lstm_rec(
    const unsigned short* __restrict__ xp, const float* __restrict__ W_hh,
    const float* __restrict__ W_fc, const float* __restrict__ b_fc,
    float* __restrict__ out) {
  __shared__ __align__(16) _Float16 h_lds[104];  // padded to 13 x uint4, pads stay 0
  __shared__ float act[G4H];

  const int tid = threadIdx.x;
  const int b   = blockIdx.x;
  const int g   = tid;

  half2v w2[52];
  if (g < G4H) {
    const float* wr = W_hh + g * HID;   // row stride 400 B, 16B-aligned
#pragma unroll
    for (int j = 0; j < 25; ++j) {
      float4 v = *(const float4*)(wr + 4 * j);
      w2[2 * j]     = (half2v){(_Float16)v.x, (_Float16)v.y};
      w2[2 * j + 1] = (half2v){(_Float16)v.z, (_Float16)v.w};
    }
    w2[50] = (half2v){(_Float16)0.f, (_Float16)0.f};
    w2[51] = (half2v){(_Float16)0.f, (_Float16)0.f};
  }
  if (tid < 104) h_lds[tid] = (_Float16)0.f;

  float c = 0.f, hreg = 0.f;
  unsigned short xpc = 0;
  const unsigned short* xpb = xp + (size_t)b * TLEN * G4H;
  if (g < G4H) xpc = xpb[g];
  __syncthreads();

  for (int t = 0; t < TLEN; ++t) {
    unsigned short xpn = 0;
    if (t + 1 < TLEN && g < G4H)
      xpn = xpb[(t + 1) * G4H + g];   // prefetch next step (HBM latency hidden)

    if (g < G4H) {
      float s0 = bf2f(xpc), s1 = 0.f, s2 = 0.f, s3 = 0.f;
      const uint4* hv = (const uint4*)h_lds;
#pragma unroll
      for (int i = 0; i < 13; ++i) {
        uint4 u = hv[i];  // 8 halves, broadcast read (no bank conflict)
        s0 = fdot2f(bch2(u.x), w2[4 * i + 0], s0);
        s1 = fdot2f(bch2(u.y), w2[4 * i + 1], s1);
        s2 = fdot2f(bch2(u.z), w2[4 * i + 2], s2);
        s3 = fdot2f(bch2(u.w), w2[4 * i + 3], s3);
      }
      float pre = (s0 + s1) + (s2 + s3);
      // gate order (i,f,g,o): sigmoid, sigmoid, tanh, sigmoid
      float a = (g < 200 || g >= 300) ? fast_sigmoid(pre) : fast_tanh(pre);
      act[g] = a;
    }
    __syncthreads();
    if (tid < HID) {
      float i_ = act[tid], f_ = act[tid + 100], g_ = act[tid + 200], o_ = act[tid + 300];
      c = f_ * c + i_ * g_;
      hreg = o_ * fast_tanh(c);
      h_lds[tid] = (_Float16)hreg;
    }
    __syncthreads();
    xpc = xpn;
  }

  // final FC: out[b][j] = h . W_fc[j] + b_fc[j]
  if (tid < HID) act[tid] = hreg;
  __syncthreads();
  if (tid < 3) {
    float s = b_fc[tid];
    const float* wf = W_fc + tid * HID;
    for (int k = 0; k < HID; ++k) s += wf[k] * act[k];
    out[b * 3 + tid] = s;
  }
}

// ---------------------------------------------------------------------------
extern "C" void kernel_launch(void* const* d_in, const int* in_sizes, int n_in,
                              void* d_out, int out_size, void* d_ws, size_t ws_size,
                              hipStream_t stream) {
  const float* x    = (const float*)d_in[0];
  const float* W_ih = (const float*)d_in[1];
  const float* W_hh = (const float*)d_in[2];
  const float* b_ih = (const float*)d_in[3];
  const float* b_hh = (const float*)d_in[4];
  const float* W_fc = (const float*)d_in[5];
  const float* b_fc = (const float*)d_in[6];
  float* out = (float*)d_out;

  // workspace layout (all 16B-aligned):
  //   xp    : bf16 [65536][400]          = 52,428,800 B
  //   Wb    : bf16 [63][416][40]         =  2,096,640 B
  //   biasb : f32  [416]                 =      1,664 B
  unsigned short* xp = (unsigned short*)d_ws;
  unsigned short* Wb = xp + (size_t)MROWS * G4H;
  float* biasb = (float*)(Wb + (size_t)KT * NPADW * LD);

  prep_kernel<<<(KT * NPADW * LD + 255) / 256, 256, 0, stream>>>(W_ih, b_ih, b_hh, Wb, biasb);
  gemm_xproj<<<MROWS / 128, 512, 0, stream>>>(x, Wb, biasb, xp);
  lstm_rec<<<BATCH, 448, 0, stream>>>(xp, W_hh, W_fc, b_fc, out);
}